// Round 3
// baseline (388.918 us; speedup 1.0000x reference)
//
#include <hip/hip_runtime.h>
#include <hip/hip_bf16.h>
#include <hip/hip_fp16.h>

#define N_NODES 100000
#define N_EDGES 3200000
#define NB      100
#define NPG     1000
#define EPG     32000    // edges per graph
#define DIN     128
#define DH      64
#define DE      32
#define NCLS    10
#define SCAT_BLOCKS 832  // 8 slices x 104 (8*13)

// XCD-affine swizzle: graph g lives on XCD g%8 (blockIdx%8 = dispatch
// round-robin), keeping each graph's working set in ONE XCD's 4MB L2.
// Aggregation = node-per-wave PULL gather from L2 (R7). R11: fp16 gather rows.
// R14: packed (src|fp16 dinv) edge recs. R16: agg MACs via v_dot2_f32_f16
// over edge pairs (DOT8), perm-packed coefs. R17: gemm1 on MFMA
// (v_mfma_f32_16x16x32_f16), W^T fp16 in LDS with XOR swizzle.
// R18: the 1-block-per-graph LDS counting sort WAS the k_sg critical path
// (61us, occupancy 42%, VALU 7%). Replaced with 3-phase parallel CSR build:
// k_cnt (8 slice-blocks/graph -> cnt8, non-atomic merge), k_scan (deg sum,
// scan, cursor=rowptr), and scatter via GLOBAL atomic cursors (8 blocks/graph)
// fused with gemm1. Within-segment edge order is arbitrary -- aggregation is
// order-independent (same property the old multi-wave LDS-atomic sort had).
// Also: W-staging rewritten lane=column, ushort4 along k -> kills the 4.9M
// LDS bank conflicts of R17's scalar-half staging.

typedef _Float16 h2_t __attribute__((ext_vector_type(2)));
typedef _Float16 h8_t __attribute__((ext_vector_type(8)));
typedef float    f4_t __attribute__((ext_vector_type(4)));

__device__ __forceinline__ float dot2f(unsigned a, unsigned b, float c) {
#if __has_builtin(__builtin_amdgcn_fdot2)
    return __builtin_amdgcn_fdot2(__builtin_bit_cast(h2_t, a),
                                  __builtin_bit_cast(h2_t, b), c, false);
#else
    float d;
    asm("v_dot2_f32_f16 %0, %1, %2, %3" : "=v"(d) : "v"(a), "v"(b), "v"(c));
    return d;
#endif
}

// rA = edge A uint4 (8 halfs), rB = edge B, dv = half2(dvA, dvB).
// perm sel: src1 bytes are idx 0..3, src0 bytes idx 4..7.
// 0x05040100 -> (lo16(rA), lo16(rB));  0x07060302 -> (hi16(rA), hi16(rB)).
#define DOT8(rA, rB, dv)                                                        \
    acc[0] = dot2f(__builtin_amdgcn_perm(rB.x, rA.x, 0x05040100u), dv, acc[0]); \
    acc[1] = dot2f(__builtin_amdgcn_perm(rB.x, rA.x, 0x07060302u), dv, acc[1]); \
    acc[2] = dot2f(__builtin_amdgcn_perm(rB.y, rA.y, 0x05040100u), dv, acc[2]); \
    acc[3] = dot2f(__builtin_amdgcn_perm(rB.y, rA.y, 0x07060302u), dv, acc[3]); \
    acc[4] = dot2f(__builtin_amdgcn_perm(rB.z, rA.z, 0x05040100u), dv, acc[4]); \
    acc[5] = dot2f(__builtin_amdgcn_perm(rB.z, rA.z, 0x07060302u), dv, acc[5]); \
    acc[6] = dot2f(__builtin_amdgcn_perm(rB.w, rA.w, 0x05040100u), dv, acc[6]); \
    acc[7] = dot2f(__builtin_amdgcn_perm(rB.w, rA.w, 0x07060302u), dv, acc[7]);

// ---------------- Phase 1: per-slice degree count ----------------
// block = (graph g, slice sub): counts its 4000-edge slice into LDS, writes
// cnt8[sub][node] non-atomically (merged in k_scan).

__global__ __launch_bounds__(256) void k_cnt(const int* __restrict__ dst,
                                             int* __restrict__ cnt8) {
    __shared__ int cnt[NPG];
    int slice = blockIdx.x >> 3;
    int g = (blockIdx.x & 7) + 8 * (slice % 13);
    int sub = slice / 13;                     // 0..7
    if (g >= NB) return;
    int t = threadIdx.x;
    for (int i = t; i < NPG; i += 256) cnt[i] = 0;
    __syncthreads();
    int ebase = g * EPG + sub * 4000, nbase = g * NPG;
    for (int i = t; i < 4000; i += 256)
        atomicAdd(&cnt[dst[ebase + i] - nbase], 1);
    __syncthreads();
    for (int i = t; i < NPG; i += 256)
        cnt8[sub * N_NODES + nbase + i] = cnt[i];
}

// ---------------- Phase 2: deg sum, scan -> rowptr/cursor, dinv/dh16 ----------------

__global__ __launch_bounds__(1024) void k_scan(const int* __restrict__ cnt8,
                                               int* __restrict__ rowptr,
                                               int* __restrict__ cursor,
                                               float* __restrict__ dinv,
                                               unsigned short* __restrict__ dh16) {
    __shared__ int sm[1024];
    int g = (blockIdx.x & 7) + 8 * (blockIdx.x >> 3);
    if (g >= NB) return;
    int t = threadIdx.x;
    int nbase = g * NPG, ebase = g * EPG;
    int v = 0;
    if (t < NPG) {
        #pragma unroll
        for (int s8 = 0; s8 < 8; s8++) v += cnt8[s8 * N_NODES + nbase + t];
        float dv = rsqrtf((float)v + 2.0f);
        dinv[nbase + t] = dv;
        dh16[nbase + t] = __half_as_ushort(__float2half_rn(dv));
    }
    sm[t] = v;
    __syncthreads();
    for (int off = 1; off < 1024; off <<= 1) {
        int xx = (t >= off) ? sm[t - off] : 0;
        __syncthreads();
        sm[t] += xx;
        __syncthreads();
    }
    if (t < NPG) {
        int ex = ebase + sm[t] - v;
        rowptr[nbase + t] = ex;
        cursor[nbase + t] = ex;
    }
    if (g == NB - 1 && t == 0) rowptr[N_NODES] = N_EDGES;
}

// ---------------- Phase 3 fused: edge scatter + MFMA GEMM1 ----------------
// blocks [0,832): scatter slice (g,sub) via global atomic cursor.
// blocks [832, 832+416): gemm1, 250 rows each (16 waves x 16 rows).
// Edge record: uint32 = (src_local*16) | (fp16(dinv[src]) << 16).

__global__ __launch_bounds__(1024) void k_sg(const int* __restrict__ src,
                                             const int* __restrict__ dst,
                                             const float* __restrict__ x,
                                             const float* __restrict__ Wa,
                                             const float* __restrict__ Wx,
                                             int* __restrict__ cursor,
                                             const unsigned short* __restrict__ dh16,
                                             unsigned int* __restrict__ esrc,
                                             unsigned short* __restrict__ h16) {
    __shared__ __align__(16) unsigned short wt[16384];  // fp16 W^T [c][k], swizzled
    int t = threadIdx.x;
    if (blockIdx.x < SCAT_BLOCKS) {
        // ---------------- scatter path ----------------
        int slice = blockIdx.x >> 3;
        int g = (blockIdx.x & 7) + 8 * (slice % 13);
        int sub = slice / 13;
        if (g >= NB) return;
        int ebase = g * EPG + sub * 4000, nbase = g * NPG;
        for (int i = t; i < 4000; i += 1024) {
            int e = ebase + i;
            int d = dst[e];
            int s = src[e];
            int pos = atomicAdd(&cursor[d], 1);
            unsigned rec = ((unsigned)(s - nbase) * 16) | ((unsigned)dh16[s] << 16);
            esrc[pos] = rec;
        }
    } else {
        // ------------- gemm1 path (MFMA): h16 = fp16( x @ [W_a1 | W_x1] ) -------------
        int b2 = blockIdx.x - SCAT_BLOCKS;         // 8*13*4 blocks
        int xcd = b2 & 7, slot = b2 >> 3;
        int g = xcd + 8 * (slot >> 2);
        int chunk = slot & 3;                       // 4 x 250-row chunks/graph
        if (g >= NB) return;
        int row0 = g * NPG + chunk * 250;
        // stage W^T fp16 in LDS, layout [c][k], byte ^= (c&7)<<4.
        // lane = column cc -> coalesced global reads per k; ushort4 writes along k.
        {
            int cc = t & 127, kg = t >> 7;          // kg 0..7 -> k block of 16
            const float* Wp = (cc < 64) ? &Wa[cc] : &Wx[cc - 64];
            #pragma unroll
            for (int j = 0; j < 4; j++) {
                int k0 = kg * 16 + j * 4;
                union { __half h[4]; uint2 u; } pk;
                #pragma unroll
                for (int m = 0; m < 4; m++)
                    pk.h[m] = __float2half_rn(Wp[(k0 + m) * 64]);
                int byte = cc * 256 + ((2 * k0) ^ ((cc & 7) << 4));
                *(uint2*)((char*)wt + byte) = pk.u;
            }
        }
        __syncthreads();
        int w = t >> 6, l = t & 63;
        int lr = l & 15, kq = l >> 4;               // A/B row|col, k-quarter
        int rowA = row0 + w * 16 + lr;
        int rA = rowA < N_NODES ? rowA : N_NODES - 1;
        const float* xr = &x[(size_t)rA * 128];
        h8_t a[4];
        #pragma unroll
        for (int kc = 0; kc < 4; kc++) {
            float4 lo = *(const float4*)&xr[kc * 32 + kq * 8];
            float4 hi = *(const float4*)&xr[kc * 32 + kq * 8 + 4];
            h8_t av;
            av[0] = (_Float16)lo.x; av[1] = (_Float16)lo.y;
            av[2] = (_Float16)lo.z; av[3] = (_Float16)lo.w;
            av[4] = (_Float16)hi.x; av[5] = (_Float16)hi.y;
            av[6] = (_Float16)hi.z; av[7] = (_Float16)hi.w;
            a[kc] = av;
        }
        f4_t acc[8] = {};
        #pragma unroll
        for (int kc = 0; kc < 4; kc++) {
            #pragma unroll
            for (int n = 0; n < 8; n++) {
                int cc = n * 16 + lr;
                int byte = cc * 256 + (((kc * 32 + kq * 8) * 2) ^ ((cc & 7) << 4));
                h8_t bf = *(h8_t*)((char*)wt + byte);
                acc[n] = __builtin_amdgcn_mfma_f32_16x16x32_f16(a[kc], bf, acc[n], 0, 0, 0);
            }
        }
        // D: col = lane&15 (=lr), row = 4*kq + reg
        int rowD = row0 + w * 16 + kq * 4;
        #pragma unroll
        for (int n = 0; n < 8; n++) {
            #pragma unroll
            for (int j = 0; j < 4; j++) {
                int r = rowD + j;
                if (r < N_NODES)
                    h16[(size_t)r * 128 + n * 16 + lr] =
                        __half_as_ushort(__float2half_rn(acc[n][j]));
            }
        }
    }
}

// ---------------- Aggregation, 128 channels (layer 1) ----------------
// Wave = 1 node; sub 0..3 edge-parallel; cl = uint4 channel group 0..15.
// Edge record gives pre-scaled uint4 offset + fp16 coef in one load.
// R16: MACs via v_dot2_f32_f16 over edge pairs (see DOT8).

__global__ __launch_bounds__(256) void k_agg128(const unsigned short* __restrict__ h16,
                                                const int* __restrict__ rowptr,
                                                const unsigned int* __restrict__ esrc,
                                                const float* __restrict__ dinv,
                                                const float* __restrict__ ba,
                                                const float* __restrict__ bx,
                                                unsigned short* __restrict__ outB16) {
    int xcd = blockIdx.x & 7, slot = blockIdx.x >> 3;
    int gi = slot / 250, chunk = slot - gi * 250;
    int g = xcd + 8 * gi;
    if (g >= NB) return;
    int nl   = chunk * 4 + (threadIdx.x >> 6);   // local node 0..999
    int wid  = g * NPG + nl;
    int lane = threadIdx.x & 63;
    int sub = lane >> 4;           // 0..3: edge j%4
    int cl  = lane & 15;           // uint4 channel group
    const uint4* hg4 = (const uint4*)(h16 + g * NPG * 128);
    float acc[8] = {};
    union U8 { uint4 u; __half h[8]; };
    int e0 = rowptr[wid], e1 = rowptr[wid + 1];
    int e = e0;
    for (; e + 16 <= e1; e += 16) {
        unsigned pv0 = esrc[e + sub];
        unsigned pv1 = esrc[e + 4 + sub];
        unsigned pv2 = esrc[e + 8 + sub];
        unsigned pv3 = esrc[e + 12 + sub];
        uint4 r0 = hg4[(pv0 & 0xffffu) + cl];
        uint4 r1 = hg4[(pv1 & 0xffffu) + cl];
        uint4 r2 = hg4[(pv2 & 0xffffu) + cl];
        uint4 r3 = hg4[(pv3 & 0xffffu) + cl];
        unsigned dA = __builtin_amdgcn_perm(pv1, pv0, 0x07060302u);  // (dv0, dv1)
        unsigned dB = __builtin_amdgcn_perm(pv3, pv2, 0x07060302u);  // (dv2, dv3)
        DOT8(r0, r1, dA);
        DOT8(r2, r3, dB);
    }
    for (; e + 8 <= e1; e += 8) {
        unsigned pv0 = esrc[e + sub];
        unsigned pv1 = esrc[e + 4 + sub];
        uint4 r0 = hg4[(pv0 & 0xffffu) + cl];
        uint4 r1 = hg4[(pv1 & 0xffffu) + cl];
        unsigned dA = __builtin_amdgcn_perm(pv1, pv0, 0x07060302u);
        DOT8(r0, r1, dA);
    }
    for (; e < e1; e += 4) {
        int ee = e + sub;
        unsigned pv; float scale;
        if (ee < e1) { pv = esrc[ee]; scale = 1.0f; }
        else         { pv = esrc[e];  scale = 0.0f; }
        U8 r; r.u = hg4[(pv & 0xffffu) + cl];
        float dv = scale * __half2float(__ushort_as_half((unsigned short)(pv >> 16)));
        #pragma unroll
        for (int k = 0; k < 8; k++)
            acc[k] += dv * __half2float(r.h[k]);
    }
    #pragma unroll
    for (int k = 0; k < 8; k++) {
        acc[k] += __shfl_xor(acc[k], 16);
        acc[k] += __shfl_xor(acc[k], 32);
    }
    if (sub == 0) {
        float di = dinv[wid];
        float sw = 2.0f * di * di;
        U8 hv; hv.u = hg4[nl * 16 + cl];
        int cl8 = cl * 8;
        const float* bb = (cl8 < 64) ? &ba[cl8] : &bx[cl8 - 64];
        union { __half2 h[4]; uint4 q; } pk;
        #pragma unroll
        for (int k = 0; k < 4; k++) {
            float ox = fmaxf(di * acc[2 * k]     + sw * __half2float(hv.h[2 * k])     + bb[2 * k],     0.0f);
            float oy = fmaxf(di * acc[2 * k + 1] + sw * __half2float(hv.h[2 * k + 1]) + bb[2 * k + 1], 0.0f);
            pk.h[k] = __floats2half2_rn(ox, oy);
        }
        *(uint4*)&outB16[wid * 128 + cl8] = pk.q;
    }
}

// ---------------- Aggregation, 64 channels (layer 2) ----------------
// sub 0..7 edge-parallel; cl = uint4 group 0..7; offset = (rec>>1) + cl.
// R16: dot2 edge-pair MACs, same scheme as k_agg128.

__global__ __launch_bounds__(256) void k_agg64(const unsigned short* __restrict__ g16,
                                               const int* __restrict__ rowptr,
                                               const unsigned int* __restrict__ esrc,
                                               const float* __restrict__ dinv,
                                               const float* __restrict__ ba2,
                                               const float* __restrict__ bx2,
                                               float* __restrict__ s2) {
    int xcd = blockIdx.x & 7, slot = blockIdx.x >> 3;
    int gi = slot / 250, chunk = slot - gi * 250;
    int g = xcd + 8 * gi;
    if (g >= NB) return;
    int nl   = chunk * 4 + (threadIdx.x >> 6);
    int wid  = g * NPG + nl;
    int lane = threadIdx.x & 63;
    int sub = lane >> 3;           // 0..7: edge j%8
    int cl  = lane & 7;            // uint4 channel group
    const uint4* gg4 = (const uint4*)(g16 + g * NPG * 64);
    float acc[8] = {};
    union U8 { uint4 u; __half h[8]; };
    int e0 = rowptr[wid], e1 = rowptr[wid + 1];
    int e = e0;
    for (; e + 16 <= e1; e += 16) {
        unsigned pv0 = esrc[e + sub];
        unsigned pv1 = esrc[e + 8 + sub];
        uint4 r0 = gg4[((pv0 & 0xffffu) >> 1) + cl];
        uint4 r1 = gg4[((pv1 & 0xffffu) >> 1) + cl];
        unsigned dA = __builtin_amdgcn_perm(pv1, pv0, 0x07060302u);
        DOT8(r0, r1, dA);
    }
    for (; e < e1; e += 8) {
        int ee = e + sub;
        unsigned pv; float scale;
        if (ee < e1) { pv = esrc[ee]; scale = 1.0f; }
        else         { pv = esrc[e];  scale = 0.0f; }
        U8 r; r.u = gg4[((pv & 0xffffu) >> 1) + cl];
        float dv = scale * __half2float(__ushort_as_half((unsigned short)(pv >> 16)));
        #pragma unroll
        for (int k = 0; k < 8; k++)
            acc[k] += dv * __half2float(r.h[k]);
    }
    #pragma unroll
    for (int k = 0; k < 8; k++) {
        acc[k] += __shfl_xor(acc[k], 8);
        acc[k] += __shfl_xor(acc[k], 16);
        acc[k] += __shfl_xor(acc[k], 32);
    }
    if (sub == 0) {
        float di = dinv[wid];
        float sw = 2.0f * di * di;
        U8 hv; hv.u = gg4[nl * 8 + cl];
        int cl8 = cl * 8;
        float o[8];
        #pragma unroll
        for (int k = 0; k < 8; k++)
            o[k] = di * acc[k] + sw * __half2float(hv.h[k]);
        if (cl8 < 32) {
            #pragma unroll
            for (int k = 0; k < 8; k++) o[k] += ba2[cl8 + k];
        } else {
            #pragma unroll
            for (int k = 0; k < 8; k++) o[k] = fmaxf(o[k] + bx2[cl8 - 32 + k], 0.0f);
        }
        *(float4*)&s2[wid * 64 + cl8]     = make_float4(o[0], o[1], o[2], o[3]);
        *(float4*)&s2[wid * 64 + cl8 + 4] = make_float4(o[4], o[5], o[6], o[7]);
    }
}

// ---------------- GEMM 2: g16 = fp16( [a1|x1] @ blockdiag(W_a2, W_x2) ) ----------------

__global__ __launch_bounds__(256) void k_gemm2(const unsigned short* __restrict__ Bm16,
                                               const float* __restrict__ Wa2,
                                               const float* __restrict__ Wx2,
                                               unsigned short* __restrict__ g16) {
    __shared__ float xs[64][132];
    __shared__ float ws[64][68];
    int xcd = blockIdx.x & 7, slot = blockIdx.x >> 3;
    int g = xcd + 8 * (slot >> 4);
    int chunk = slot & 15;
    if (g >= NB) return;
    int row0 = g * NPG + chunk * 64;   // chunk 15 spills into next graph: benign dup
    int t = threadIdx.x;
    for (int i = 0; i < 4; i++) {
        int idx = t + 256 * i;
        int k = idx >> 4, c4 = idx & 15, c = c4 * 4;
        float4 v;
        if (c < 32) v = *(const float4*)&Wa2[k * 32 + c];
        else        v = *(const float4*)&Wx2[k * 32 + (c - 32)];
        *(float4*)&ws[k][c] = v;
    }
    for (int i = 0; i < 4; i++) {
        int idx = t + 256 * i;          // 1024 uint4s = 64 rows x 16 groups
        int r = idx >> 4, c8 = idx & 15;
        int rr = row0 + r; if (rr >= N_NODES) rr = N_NODES - 1;
        union { uint4 u; __half2 h[4]; } pk;
        pk.u = *(const uint4*)&Bm16[rr * 128 + c8 * 8];
        float2 f0 = __half22float2(pk.h[0]);
        float2 f1 = __half22float2(pk.h[1]);
        float2 f2 = __half22float2(pk.h[2]);
        float2 f3 = __half22float2(pk.h[3]);
        int cb = c8 * 8;
        *(float4*)&xs[r][cb]     = make_float4(f0.x, f0.y, f1.x, f1.y);
        *(float4*)&xs[r][cb + 4] = make_float4(f2.x, f2.y, f3.x, f3.y);
    }
    __syncthreads();
    int cg = t & 15, rg = t >> 4;
    int koff = (cg < 8) ? 0 : 64;
    float acc[4][4] = {};
    for (int k = 0; k < 64; k++) {
        float4 w = *(float4*)&ws[k][cg * 4];
        float xv[4];
        for (int i = 0; i < 4; i++) xv[i] = xs[rg * 4 + i][koff + k];
        for (int i = 0; i < 4; i++) {
            acc[i][0] += xv[i] * w.x; acc[i][1] += xv[i] * w.y;
            acc[i][2] += xv[i] * w.z; acc[i][3] += xv[i] * w.w;
        }
    }
    for (int i = 0; i < 4; i++) {
        int r = row0 + rg * 4 + i;
        if (r < N_NODES) {
            union { ushort4 u; __half2 h[2]; } pk;
            pk.h[0] = __floats2half2_rn(acc[i][0], acc[i][1]);
            pk.h[1] = __floats2half2_rn(acc[i][2], acc[i][3]);
            *(ushort4*)&g16[r * 64 + cg * 4] = pk.u;
        }
    }
}

// ---------------- Segment softmax stats (cols 0..31), 512 threads ----------------

__global__ __launch_bounds__(512) void k_smax(const float* __restrict__ s2,
                                              float* __restrict__ gmax,
                                              float* __restrict__ sinv) {
    __shared__ float red[16][32];
    int g = (blockIdx.x & 7) + 8 * (blockIdx.x >> 3);
    if (g >= NB) return;
    int t = threadIdx.x;
    int c = t & 31, sub = t >> 5;     // 16 row-subsets
    size_t base = (size_t)g * NPG;
    float m = -1e30f;
    for (int n = sub; n < NPG; n += 16)
        m = fmaxf(m, s2[(base + n) * 64 + c]);
    red[sub][c] = m; __syncthreads();
    if (sub == 0) {
        for (int j = 1; j < 16; j++) m = fmaxf(m, red[j][c]);
        red[0][c] = m;
        gmax[g * 32 + c] = m;
    }
    __syncthreads();
    m = red[0][c];
    __syncthreads();
    float sum = 0.0f;
    for (int n = sub; n < NPG; n += 16)
        sum += __expf(s2[(base + n) * 64 + c] - m);
    red[sub][c] = sum; __syncthreads();
    if (sub == 0) {
        for (int j = 1; j < 16; j++) sum += red[j][c];
        sinv[g * 32 + c] = 1.0f / sum;
    }
}

// ---------------- Bilinear pool: 8 chunks/graph, 25-row tiles ----------------

__global__ __launch_bounds__(256) void k_pool(const float* __restrict__ s2,
                                              const float* __restrict__ gmax,
                                              float* __restrict__ prods) {
    __shared__ float ta[25][32];
    __shared__ float tx[25][32];
    __shared__ float gm[32];
    int xcd = blockIdx.x & 7, slot = blockIdx.x >> 3;
    int g = xcd + 8 * (slot >> 3);
    int ch = slot & 7;
    if (g >= NB) return;
    int t = threadIdx.x;
    if (t < 32) gm[t] = gmax[g * 32 + t];
    int e  = t >> 3;
    int f4 = t & 7;
    float a0 = 0.f, a1 = 0.f, a2 = 0.f, a3 = 0.f;
    int base = g * NPG + ch * 125;
    for (int n0 = 0; n0 < 125; n0 += 25) {
        __syncthreads();
        for (int i = t; i < 25 * 16; i += 256) {
            int r = i >> 4, c4 = i & 15;
            float4 v = *(const float4*)&s2[(size_t)(base + n0 + r) * 64 + c4 * 4];
            if (c4 < 8) {
                int cb = c4 * 4;
                v.x = __expf(v.x - gm[cb + 0]);
                v.y = __expf(v.y - gm[cb + 1]);
                v.z = __expf(v.z - gm[cb + 2]);
                v.w = __expf(v.w - gm[cb + 3]);
                *(float4*)&ta[r][cb] = v;
            } else {
                *(float4*)&tx[r][(c4 - 8) * 4] = v;
            }
        }
        __syncthreads();
        #pragma unroll 5
        for (int n = 0; n < 25; n++) {
            float a   = ta[n][e];
            float4 xv = *(float4*)&tx[n][f4 * 4];
            a0 += a * xv.x; a1 += a * xv.y; a2 += a * xv.z; a3 += a * xv.w;
        }
    }
    *(float4*)&prods[((size_t)(g * 8 + ch)) * 1024 + e * 32 + f4 * 4] =
        make_float4(a0, a1, a2, a3);
}

// ---------------- Head: sum 8 chunk-partials, linear, softmax ----------------

__global__ __launch_bounds__(256) void k_head(const float* __restrict__ prods,
                                              const float* __restrict__ sinv,
                                              const float* __restrict__ Wlin,
                                              const float* __restrict__ blin,
                                              float* __restrict__ out) {
    __shared__ float red[4][NCLS];
    int g = (blockIdx.x & 7) + 8 * (blockIdx.x >> 3);
    if (g >= NB) return;
    int t = threadIdx.x;
    float p[NCLS];
    for (int c = 0; c < NCLS; c++) p[c] = 0.0f;
    const float* pg = &prods[(size_t)g * 8 * 1024];
    for (int j = 0; j < 4; j++) {
        int k = t * 4 + j;
        int e = k >> 5;
        float v = 0.0f;
        #pragma unroll
        for (int q = 0; q < 8; q++) v += pg[q * 1024 + k];
        v *= sinv[g * 32 + e];
        const float* wrow = &Wlin[k * NCLS];
        for (int c = 0; c < NCLS; c++) p[c] += v * wrow[c];
    }
    for (int off = 32; off > 0; off >>= 1)
        for (int c = 0; c < NCLS; c++) p[c] += __shfl_down(p[c], off, 64);
    int wave = t >> 6, lane = t & 63;
    if (lane == 0)
        for (int c = 0; c < NCLS; c++) red[wave][c] = p[c];
    __syncthreads();
    if (t == 0) {
        float logits[NCLS]; float mx = -1e30f;
        for (int c = 0; c < NCLS; c++) {
            logits[c] = red[0][c] + red[1][c] + red[2][c] + red[3][c] + blin[c];
            mx = fmaxf(mx, logits[c]);
        }
        float s = 0.0f;
        for (int c = 0; c < NCLS; c++) { logits[c] = expf(logits[c] - mx); s += logits[c]; }
        float inv = 1.0f / s;
        for (int c = 0; c < NCLS; c++) out[g * NCLS + c] = logits[c] * inv;
    }
}

// ---------------- launch ----------------

extern "C" void kernel_launch(void* const* d_in, const int* in_sizes, int n_in,
                              void* d_out, int out_size, void* d_ws, size_t ws_size,
                              hipStream_t stream) {
    const float* x    = (const float*)d_in[0];
    const int*   ei   = (const int*)d_in[1];
    const float* Wa1  = (const float*)d_in[3];
    const float* ba1  = (const float*)d_in[4];
    const float* Wa2  = (const float*)d_in[5];
    const float* ba2  = (const float*)d_in[6];
    const float* Wx1  = (const float*)d_in[7];
    const float* bx1  = (const float*)d_in[8];
    const float* Wx2  = (const float*)d_in[9];
    const float* bx2  = (const float*)d_in[10];
    const float* Wlin = (const float*)d_in[11];
    const float* blin = (const float*)d_in[12];
    float* out = (float*)d_out;

    char* w = (char*)d_ws;
    auto alloc = [&](size_t bytes) -> void* {
        void* p = (void*)w;
        w += (bytes + 255) & ~(size_t)255;
        return p;
    };
    int*            rowptr = (int*)alloc((N_NODES + 1) * sizeof(int));
    int*            cursor = (int*)alloc(N_NODES * sizeof(int));
    int*            cnt8   = (int*)alloc((size_t)8 * N_NODES * sizeof(int));
    float*          dinv   = (float*)alloc(N_NODES * sizeof(float));
    unsigned short* dh16   = (unsigned short*)alloc(N_NODES * sizeof(unsigned short));
    unsigned int*   esrc   = (unsigned int*)alloc((size_t)N_EDGES * sizeof(unsigned int));
    float*          gmax   = (float*)alloc(NB * DE * sizeof(float));
    float*          sinv   = (float*)alloc(NB * DE * sizeof(float));
    float*          prods  = (float*)alloc((size_t)NB * 8 * 1024 * sizeof(float));
    unsigned short* h16    = (unsigned short*)alloc((size_t)N_NODES * 128 * sizeof(unsigned short));
    unsigned short* b16    = (unsigned short*)alloc((size_t)N_NODES * 128 * sizeof(unsigned short));
    unsigned short* g16    = (unsigned short*)alloc((size_t)N_NODES * 64 * sizeof(unsigned short));
    float*          s2     = (float*)alloc((size_t)N_NODES * 64 * sizeof(float));

    const int* srcp = ei;
    const int* dstp = ei + N_EDGES;

    k_cnt<<<SCAT_BLOCKS, 256, 0, stream>>>(dstp, cnt8);
    k_scan<<<8 * 13, 1024, 0, stream>>>(cnt8, rowptr, cursor, dinv, dh16);
    k_sg<<<SCAT_BLOCKS + 8 * 13 * 4, 1024, 0, stream>>>(srcp, dstp, x, Wa1, Wx1,
                                                        cursor, dh16, esrc, h16);
    k_agg128<<<8 * 13 * 250, 256, 0, stream>>>(h16, rowptr, esrc, dinv, ba1, bx1, b16);
    k_gemm2<<<8 * 13 * 16, 256, 0, stream>>>(b16, Wa2, Wx2, g16);
    k_agg64<<<8 * 13 * 250, 256, 0, stream>>>(g16, rowptr, esrc, dinv, ba2, bx2, s2);
    k_smax<<<8 * 13, 512, 0, stream>>>(s2, gmax, sinv);
    k_pool<<<8 * 13 * 8, 256, 0, stream>>>(s2, gmax, prods);
    k_head<<<8 * 13, 256, 0, stream>>>(prods, sinv, Wlin, blin, out);
}

// Round 4
// 326.471 us; speedup vs baseline: 1.1913x; 1.1913x over previous
//
#include <hip/hip_runtime.h>
#include <hip/hip_bf16.h>
#include <hip/hip_fp16.h>

#define N_NODES 100000
#define N_EDGES 3200000
#define NB      100
#define NPG     1000
#define EPG     32000    // edges per graph
#define DIN     128
#define DH      64
#define DE      32
#define NCLS    10
#define CNT_BLOCKS  832  // 8 slices x 104
#define SORT_BLOCKS 416  // 4 node-quarters x 104

// XCD-affine swizzle: graph g lives on XCD g%8 (blockIdx%8 = dispatch
// round-robin), keeping each graph's working set in ONE XCD's 4MB L2.
// Aggregation = node-per-wave PULL gather from L2 (R7). R11: fp16 gather rows.
// R14: packed (src|fp16 dinv) edge recs. R16: agg MACs via v_dot2_f32_f16
// over edge pairs (DOT8). R17: gemm1 on MFMA (v_mfma_f32_16x16x32_f16).
// R18 FAILED: global-atomic scatter -> random 4B stores under L2 pressure
// amplified WRITE_SIZE 39->166 MB (partial-line evict/writeback thrash).
// R19: parallel CSR build with LDS-staged scatter: k_cnt (8 slices/graph,
// non-atomic cnt8) -> k_scan (deg, scan -> rowptr, dinv/dh16) -> k_sg sort
// blocks (g,quarter) own nodes [q*250,(q+1)*250): inspect all 32K edges
// (L2-resident), scatter kept ~8K into LDS buf via LDS cursors seeded from
// rowptr (a node's CSR segment belongs to exactly ONE block -> no cross-block
// atomics), coalesced full-line writeout of the contiguous CSR range.
// 4x less LDS-atomic serialization than R17's 1-block/graph sort; write
// traffic back to R17 levels. gemm1 fused in the same launch hides under it.

typedef _Float16 h2_t __attribute__((ext_vector_type(2)));
typedef _Float16 h8_t __attribute__((ext_vector_type(8)));
typedef float    f4_t __attribute__((ext_vector_type(4)));

__device__ __forceinline__ float dot2f(unsigned a, unsigned b, float c) {
#if __has_builtin(__builtin_amdgcn_fdot2)
    return __builtin_amdgcn_fdot2(__builtin_bit_cast(h2_t, a),
                                  __builtin_bit_cast(h2_t, b), c, false);
#else
    float d;
    asm("v_dot2_f32_f16 %0, %1, %2, %3" : "=v"(d) : "v"(a), "v"(b), "v"(c));
    return d;
#endif
}

// rA = edge A uint4 (8 halfs), rB = edge B, dv = half2(dvA, dvB).
// perm sel: src1 bytes are idx 0..3, src0 bytes idx 4..7.
// 0x05040100 -> (lo16(rA), lo16(rB));  0x07060302 -> (hi16(rA), hi16(rB)).
#define DOT8(rA, rB, dv)                                                        \
    acc[0] = dot2f(__builtin_amdgcn_perm(rB.x, rA.x, 0x05040100u), dv, acc[0]); \
    acc[1] = dot2f(__builtin_amdgcn_perm(rB.x, rA.x, 0x07060302u), dv, acc[1]); \
    acc[2] = dot2f(__builtin_amdgcn_perm(rB.y, rA.y, 0x05040100u), dv, acc[2]); \
    acc[3] = dot2f(__builtin_amdgcn_perm(rB.y, rA.y, 0x07060302u), dv, acc[3]); \
    acc[4] = dot2f(__builtin_amdgcn_perm(rB.z, rA.z, 0x05040100u), dv, acc[4]); \
    acc[5] = dot2f(__builtin_amdgcn_perm(rB.z, rA.z, 0x07060302u), dv, acc[5]); \
    acc[6] = dot2f(__builtin_amdgcn_perm(rB.w, rA.w, 0x05040100u), dv, acc[6]); \
    acc[7] = dot2f(__builtin_amdgcn_perm(rB.w, rA.w, 0x07060302u), dv, acc[7]);

// ---------------- Phase 1: per-slice degree count ----------------
// block = (graph g, slice sub): counts its 4000-edge slice into LDS, writes
// cnt8[sub][node] non-atomically (merged in k_scan).

__global__ __launch_bounds__(256) void k_cnt(const int* __restrict__ dst,
                                             int* __restrict__ cnt8) {
    __shared__ int cnt[NPG];
    int slice = blockIdx.x >> 3;
    int g = (blockIdx.x & 7) + 8 * (slice % 13);
    int sub = slice / 13;                     // 0..7
    if (g >= NB) return;
    int t = threadIdx.x;
    for (int i = t; i < NPG; i += 256) cnt[i] = 0;
    __syncthreads();
    int ebase = g * EPG + sub * 4000, nbase = g * NPG;
    for (int i = t; i < 4000; i += 256)
        atomicAdd(&cnt[dst[ebase + i] - nbase], 1);
    __syncthreads();
    for (int i = t; i < NPG; i += 256)
        cnt8[sub * N_NODES + nbase + i] = cnt[i];
}

// ---------------- Phase 2: deg sum, scan -> rowptr, dinv/dh16 ----------------

__global__ __launch_bounds__(1024) void k_scan(const int* __restrict__ cnt8,
                                               int* __restrict__ rowptr,
                                               float* __restrict__ dinv,
                                               unsigned short* __restrict__ dh16) {
    __shared__ int sm[1024];
    int g = (blockIdx.x & 7) + 8 * (blockIdx.x >> 3);
    if (g >= NB) return;
    int t = threadIdx.x;
    int nbase = g * NPG, ebase = g * EPG;
    int v = 0;
    if (t < NPG) {
        #pragma unroll
        for (int s8 = 0; s8 < 8; s8++) v += cnt8[s8 * N_NODES + nbase + t];
        float dv = rsqrtf((float)v + 2.0f);
        dinv[nbase + t] = dv;
        dh16[nbase + t] = __half_as_ushort(__float2half_rn(dv));
    }
    sm[t] = v;
    __syncthreads();
    for (int off = 1; off < 1024; off <<= 1) {
        int xx = (t >= off) ? sm[t - off] : 0;
        __syncthreads();
        sm[t] += xx;
        __syncthreads();
    }
    if (t < NPG)
        rowptr[nbase + t] = ebase + sm[t] - v;
    if (g == NB - 1 && t == 0) rowptr[N_NODES] = N_EDGES;
}

// ---------------- Phase 3 fused: LDS-staged edge scatter + MFMA GEMM1 ----------------
// blocks [0,416): sort quarter (g,q) -- nodes [q*250,(q+1)*250).
// blocks [416, 832): gemm1, 250 rows each (16 waves x 16 rows).
// Edge record: uint32 = (src_local*16) | (fp16(dinv[src]) << 16).

union SharedSG {
    struct {
        int cur[256];                            // LDS cursors (local offsets)
        unsigned buf[10000];                     // staged records (cap >> max seg)
    } sc;
    struct {
        __align__(16) unsigned short wt[16384];  // fp16 W^T [c][k], swizzled
    } ge;
};

__global__ __launch_bounds__(1024) void k_sg(const int* __restrict__ src,
                                             const int* __restrict__ dst,
                                             const float* __restrict__ x,
                                             const float* __restrict__ Wa,
                                             const float* __restrict__ Wx,
                                             const int* __restrict__ rowptr,
                                             const unsigned short* __restrict__ dh16,
                                             unsigned int* __restrict__ esrc,
                                             unsigned short* __restrict__ h16) {
    __shared__ SharedSG S;
    int t = threadIdx.x;
    if (blockIdx.x < SORT_BLOCKS) {
        // ---------------- scatter path ----------------
        int xcd = blockIdx.x & 7, slot = blockIdx.x >> 3;
        int g = xcd + 8 * (slot % 13);
        int q = slot / 13;                       // node quarter 0..3
        if (g >= NB) return;
        int nbase = g * NPG, ebase = g * EPG;
        int n0 = q * 250;
        int base0 = rowptr[nbase + n0];
        int cap = rowptr[nbase + n0 + 250] - base0;
        if (t < 250)
            S.sc.cur[t] = rowptr[nbase + n0 + t] - base0;
        __syncthreads();
        for (int i = t; i < EPG; i += 1024) {
            int d = dst[ebase + i] - nbase - n0;
            if ((unsigned)d < 250u) {
                int s = src[ebase + i];
                int pos = atomicAdd(&S.sc.cur[d], 1);
                S.sc.buf[pos] = ((unsigned)(s - nbase) * 16) |
                                ((unsigned)dh16[s] << 16);
            }
        }
        __syncthreads();
        for (int i = t; i < cap; i += 1024)
            esrc[base0 + i] = S.sc.buf[i];
    } else {
        // ------------- gemm1 path (MFMA): h16 = fp16( x @ [W_a1 | W_x1] ) -------------
        int b2 = blockIdx.x - SORT_BLOCKS;         // 8*13*4 blocks
        int xcd = b2 & 7, slot = b2 >> 3;
        int g = xcd + 8 * (slot >> 2);
        int chunk = slot & 3;                       // 4 x 250-row chunks/graph
        if (g >= NB) return;
        int row0 = g * NPG + chunk * 250;
        // stage W^T fp16 in LDS, layout [c][k], byte ^= (c&7)<<4.
        // lane = column cc -> coalesced global reads per k; uint2 writes along k.
        {
            int cc = t & 127, kg = t >> 7;          // kg 0..7 -> k block of 16
            const float* Wp = (cc < 64) ? &Wa[cc] : &Wx[cc - 64];
            #pragma unroll
            for (int j = 0; j < 4; j++) {
                int k0 = kg * 16 + j * 4;
                union { __half h[4]; uint2 u; } pk;
                #pragma unroll
                for (int m = 0; m < 4; m++)
                    pk.h[m] = __float2half_rn(Wp[(k0 + m) * 64]);
                int byte = cc * 256 + ((2 * k0) ^ ((cc & 7) << 4));
                *(uint2*)((char*)S.ge.wt + byte) = pk.u;
            }
        }
        __syncthreads();
        int w = t >> 6, l = t & 63;
        int lr = l & 15, kq = l >> 4;               // A/B row|col, k-quarter
        int rowA = row0 + w * 16 + lr;
        int rA = rowA < N_NODES ? rowA : N_NODES - 1;
        const float* xr = &x[(size_t)rA * 128];
        h8_t a[4];
        #pragma unroll
        for (int kc = 0; kc < 4; kc++) {
            float4 lo = *(const float4*)&xr[kc * 32 + kq * 8];
            float4 hi = *(const float4*)&xr[kc * 32 + kq * 8 + 4];
            h8_t av;
            av[0] = (_Float16)lo.x; av[1] = (_Float16)lo.y;
            av[2] = (_Float16)lo.z; av[3] = (_Float16)lo.w;
            av[4] = (_Float16)hi.x; av[5] = (_Float16)hi.y;
            av[6] = (_Float16)hi.z; av[7] = (_Float16)hi.w;
            a[kc] = av;
        }
        f4_t acc[8] = {};
        #pragma unroll
        for (int kc = 0; kc < 4; kc++) {
            #pragma unroll
            for (int n = 0; n < 8; n++) {
                int cc = n * 16 + lr;
                int byte = cc * 256 + (((kc * 32 + kq * 8) * 2) ^ ((cc & 7) << 4));
                h8_t bf = *(h8_t*)((char*)S.ge.wt + byte);
                acc[n] = __builtin_amdgcn_mfma_f32_16x16x32_f16(a[kc], bf, acc[n], 0, 0, 0);
            }
        }
        // D: col = lane&15 (=lr), row = 4*kq + reg
        int rowD = row0 + w * 16 + kq * 4;
        #pragma unroll
        for (int n = 0; n < 8; n++) {
            #pragma unroll
            for (int j = 0; j < 4; j++) {
                int r = rowD + j;
                if (r < N_NODES)
                    h16[(size_t)r * 128 + n * 16 + lr] =
                        __half_as_ushort(__float2half_rn(acc[n][j]));
            }
        }
    }
}

// ---------------- Aggregation, 128 channels (layer 1) ----------------
// Wave = 1 node; sub 0..3 edge-parallel; cl = uint4 channel group 0..15.
// Edge record gives pre-scaled uint4 offset + fp16 coef in one load.
// R16: MACs via v_dot2_f32_f16 over edge pairs (see DOT8).

__global__ __launch_bounds__(256) void k_agg128(const unsigned short* __restrict__ h16,
                                                const int* __restrict__ rowptr,
                                                const unsigned int* __restrict__ esrc,
                                                const float* __restrict__ dinv,
                                                const float* __restrict__ ba,
                                                const float* __restrict__ bx,
                                                unsigned short* __restrict__ outB16) {
    int xcd = blockIdx.x & 7, slot = blockIdx.x >> 3;
    int gi = slot / 250, chunk = slot - gi * 250;
    int g = xcd + 8 * gi;
    if (g >= NB) return;
    int nl   = chunk * 4 + (threadIdx.x >> 6);   // local node 0..999
    int wid  = g * NPG + nl;
    int lane = threadIdx.x & 63;
    int sub = lane >> 4;           // 0..3: edge j%4
    int cl  = lane & 15;           // uint4 channel group
    const uint4* hg4 = (const uint4*)(h16 + g * NPG * 128);
    float acc[8] = {};
    union U8 { uint4 u; __half h[8]; };
    int e0 = rowptr[wid], e1 = rowptr[wid + 1];
    int e = e0;
    for (; e + 16 <= e1; e += 16) {
        unsigned pv0 = esrc[e + sub];
        unsigned pv1 = esrc[e + 4 + sub];
        unsigned pv2 = esrc[e + 8 + sub];
        unsigned pv3 = esrc[e + 12 + sub];
        uint4 r0 = hg4[(pv0 & 0xffffu) + cl];
        uint4 r1 = hg4[(pv1 & 0xffffu) + cl];
        uint4 r2 = hg4[(pv2 & 0xffffu) + cl];
        uint4 r3 = hg4[(pv3 & 0xffffu) + cl];
        unsigned dA = __builtin_amdgcn_perm(pv1, pv0, 0x07060302u);  // (dv0, dv1)
        unsigned dB = __builtin_amdgcn_perm(pv3, pv2, 0x07060302u);  // (dv2, dv3)
        DOT8(r0, r1, dA);
        DOT8(r2, r3, dB);
    }
    for (; e + 8 <= e1; e += 8) {
        unsigned pv0 = esrc[e + sub];
        unsigned pv1 = esrc[e + 4 + sub];
        uint4 r0 = hg4[(pv0 & 0xffffu) + cl];
        uint4 r1 = hg4[(pv1 & 0xffffu) + cl];
        unsigned dA = __builtin_amdgcn_perm(pv1, pv0, 0x07060302u);
        DOT8(r0, r1, dA);
    }
    for (; e < e1; e += 4) {
        int ee = e + sub;
        unsigned pv; float scale;
        if (ee < e1) { pv = esrc[ee]; scale = 1.0f; }
        else         { pv = esrc[e];  scale = 0.0f; }
        U8 r; r.u = hg4[(pv & 0xffffu) + cl];
        float dv = scale * __half2float(__ushort_as_half((unsigned short)(pv >> 16)));
        #pragma unroll
        for (int k = 0; k < 8; k++)
            acc[k] += dv * __half2float(r.h[k]);
    }
    #pragma unroll
    for (int k = 0; k < 8; k++) {
        acc[k] += __shfl_xor(acc[k], 16);
        acc[k] += __shfl_xor(acc[k], 32);
    }
    if (sub == 0) {
        float di = dinv[wid];
        float sw = 2.0f * di * di;
        U8 hv; hv.u = hg4[nl * 16 + cl];
        int cl8 = cl * 8;
        const float* bb = (cl8 < 64) ? &ba[cl8] : &bx[cl8 - 64];
        union { __half2 h[4]; uint4 q; } pk;
        #pragma unroll
        for (int k = 0; k < 4; k++) {
            float ox = fmaxf(di * acc[2 * k]     + sw * __half2float(hv.h[2 * k])     + bb[2 * k],     0.0f);
            float oy = fmaxf(di * acc[2 * k + 1] + sw * __half2float(hv.h[2 * k + 1]) + bb[2 * k + 1], 0.0f);
            pk.h[k] = __floats2half2_rn(ox, oy);
        }
        *(uint4*)&outB16[wid * 128 + cl8] = pk.q;
    }
}

// ---------------- Aggregation, 64 channels (layer 2) ----------------
// sub 0..7 edge-parallel; cl = uint4 group 0..7; offset = (rec>>1) + cl.
// R16: dot2 edge-pair MACs, same scheme as k_agg128.

__global__ __launch_bounds__(256) void k_agg64(const unsigned short* __restrict__ g16,
                                               const int* __restrict__ rowptr,
                                               const unsigned int* __restrict__ esrc,
                                               const float* __restrict__ dinv,
                                               const float* __restrict__ ba2,
                                               const float* __restrict__ bx2,
                                               float* __restrict__ s2) {
    int xcd = blockIdx.x & 7, slot = blockIdx.x >> 3;
    int gi = slot / 250, chunk = slot - gi * 250;
    int g = xcd + 8 * gi;
    if (g >= NB) return;
    int nl   = chunk * 4 + (threadIdx.x >> 6);
    int wid  = g * NPG + nl;
    int lane = threadIdx.x & 63;
    int sub = lane >> 3;           // 0..7: edge j%8
    int cl  = lane & 7;            // uint4 channel group
    const uint4* gg4 = (const uint4*)(g16 + g * NPG * 64);
    float acc[8] = {};
    union U8 { uint4 u; __half h[8]; };
    int e0 = rowptr[wid], e1 = rowptr[wid + 1];
    int e = e0;
    for (; e + 16 <= e1; e += 16) {
        unsigned pv0 = esrc[e + sub];
        unsigned pv1 = esrc[e + 8 + sub];
        uint4 r0 = gg4[((pv0 & 0xffffu) >> 1) + cl];
        uint4 r1 = gg4[((pv1 & 0xffffu) >> 1) + cl];
        unsigned dA = __builtin_amdgcn_perm(pv1, pv0, 0x07060302u);
        DOT8(r0, r1, dA);
    }
    for (; e < e1; e += 8) {
        int ee = e + sub;
        unsigned pv; float scale;
        if (ee < e1) { pv = esrc[ee]; scale = 1.0f; }
        else         { pv = esrc[e];  scale = 0.0f; }
        U8 r; r.u = gg4[((pv & 0xffffu) >> 1) + cl];
        float dv = scale * __half2float(__ushort_as_half((unsigned short)(pv >> 16)));
        #pragma unroll
        for (int k = 0; k < 8; k++)
            acc[k] += dv * __half2float(r.h[k]);
    }
    #pragma unroll
    for (int k = 0; k < 8; k++) {
        acc[k] += __shfl_xor(acc[k], 8);
        acc[k] += __shfl_xor(acc[k], 16);
        acc[k] += __shfl_xor(acc[k], 32);
    }
    if (sub == 0) {
        float di = dinv[wid];
        float sw = 2.0f * di * di;
        U8 hv; hv.u = gg4[nl * 8 + cl];
        int cl8 = cl * 8;
        float o[8];
        #pragma unroll
        for (int k = 0; k < 8; k++)
            o[k] = di * acc[k] + sw * __half2float(hv.h[k]);
        if (cl8 < 32) {
            #pragma unroll
            for (int k = 0; k < 8; k++) o[k] += ba2[cl8 + k];
        } else {
            #pragma unroll
            for (int k = 0; k < 8; k++) o[k] = fmaxf(o[k] + bx2[cl8 - 32 + k], 0.0f);
        }
        *(float4*)&s2[wid * 64 + cl8]     = make_float4(o[0], o[1], o[2], o[3]);
        *(float4*)&s2[wid * 64 + cl8 + 4] = make_float4(o[4], o[5], o[6], o[7]);
    }
}

// ---------------- GEMM 2: g16 = fp16( [a1|x1] @ blockdiag(W_a2, W_x2) ) ----------------

__global__ __launch_bounds__(256) void k_gemm2(const unsigned short* __restrict__ Bm16,
                                               const float* __restrict__ Wa2,
                                               const float* __restrict__ Wx2,
                                               unsigned short* __restrict__ g16) {
    __shared__ float xs[64][132];
    __shared__ float ws[64][68];
    int xcd = blockIdx.x & 7, slot = blockIdx.x >> 3;
    int g = xcd + 8 * (slot >> 4);
    int chunk = slot & 15;
    if (g >= NB) return;
    int row0 = g * NPG + chunk * 64;   // chunk 15 spills into next graph: benign dup
    int t = threadIdx.x;
    for (int i = 0; i < 4; i++) {
        int idx = t + 256 * i;
        int k = idx >> 4, c4 = idx & 15, c = c4 * 4;
        float4 v;
        if (c < 32) v = *(const float4*)&Wa2[k * 32 + c];
        else        v = *(const float4*)&Wx2[k * 32 + (c - 32)];
        *(float4*)&ws[k][c] = v;
    }
    for (int i = 0; i < 4; i++) {
        int idx = t + 256 * i;          // 1024 uint4s = 64 rows x 16 groups
        int r = idx >> 4, c8 = idx & 15;
        int rr = row0 + r; if (rr >= N_NODES) rr = N_NODES - 1;
        union { uint4 u; __half2 h[4]; } pk;
        pk.u = *(const uint4*)&Bm16[rr * 128 + c8 * 8];
        float2 f0 = __half22float2(pk.h[0]);
        float2 f1 = __half22float2(pk.h[1]);
        float2 f2 = __half22float2(pk.h[2]);
        float2 f3 = __half22float2(pk.h[3]);
        int cb = c8 * 8;
        *(float4*)&xs[r][cb]     = make_float4(f0.x, f0.y, f1.x, f1.y);
        *(float4*)&xs[r][cb + 4] = make_float4(f2.x, f2.y, f3.x, f3.y);
    }
    __syncthreads();
    int cg = t & 15, rg = t >> 4;
    int koff = (cg < 8) ? 0 : 64;
    float acc[4][4] = {};
    for (int k = 0; k < 64; k++) {
        float4 w = *(float4*)&ws[k][cg * 4];
        float xv[4];
        for (int i = 0; i < 4; i++) xv[i] = xs[rg * 4 + i][koff + k];
        for (int i = 0; i < 4; i++) {
            acc[i][0] += xv[i] * w.x; acc[i][1] += xv[i] * w.y;
            acc[i][2] += xv[i] * w.z; acc[i][3] += xv[i] * w.w;
        }
    }
    for (int i = 0; i < 4; i++) {
        int r = row0 + rg * 4 + i;
        if (r < N_NODES) {
            union { ushort4 u; __half2 h[2]; } pk;
            pk.h[0] = __floats2half2_rn(acc[i][0], acc[i][1]);
            pk.h[1] = __floats2half2_rn(acc[i][2], acc[i][3]);
            *(ushort4*)&g16[r * 64 + cg * 4] = pk.u;
        }
    }
}

// ---------------- Segment softmax stats (cols 0..31), 512 threads ----------------

__global__ __launch_bounds__(512) void k_smax(const float* __restrict__ s2,
                                              float* __restrict__ gmax,
                                              float* __restrict__ sinv) {
    __shared__ float red[16][32];
    int g = (blockIdx.x & 7) + 8 * (blockIdx.x >> 3);
    if (g >= NB) return;
    int t = threadIdx.x;
    int c = t & 31, sub = t >> 5;     // 16 row-subsets
    size_t base = (size_t)g * NPG;
    float m = -1e30f;
    for (int n = sub; n < NPG; n += 16)
        m = fmaxf(m, s2[(base + n) * 64 + c]);
    red[sub][c] = m; __syncthreads();
    if (sub == 0) {
        for (int j = 1; j < 16; j++) m = fmaxf(m, red[j][c]);
        red[0][c] = m;
        gmax[g * 32 + c] = m;
    }
    __syncthreads();
    m = red[0][c];
    __syncthreads();
    float sum = 0.0f;
    for (int n = sub; n < NPG; n += 16)
        sum += __expf(s2[(base + n) * 64 + c] - m);
    red[sub][c] = sum; __syncthreads();
    if (sub == 0) {
        for (int j = 1; j < 16; j++) sum += red[j][c];
        sinv[g * 32 + c] = 1.0f / sum;
    }
}

// ---------------- Bilinear pool: 8 chunks/graph, 25-row tiles ----------------

__global__ __launch_bounds__(256) void k_pool(const float* __restrict__ s2,
                                              const float* __restrict__ gmax,
                                              float* __restrict__ prods) {
    __shared__ float ta[25][32];
    __shared__ float tx[25][32];
    __shared__ float gm[32];
    int xcd = blockIdx.x & 7, slot = blockIdx.x >> 3;
    int g = xcd + 8 * (slot >> 3);
    int ch = slot & 7;
    if (g >= NB) return;
    int t = threadIdx.x;
    if (t < 32) gm[t] = gmax[g * 32 + t];
    int e  = t >> 3;
    int f4 = t & 7;
    float a0 = 0.f, a1 = 0.f, a2 = 0.f, a3 = 0.f;
    int base = g * NPG + ch * 125;
    for (int n0 = 0; n0 < 125; n0 += 25) {
        __syncthreads();
        for (int i = t; i < 25 * 16; i += 256) {
            int r = i >> 4, c4 = i & 15;
            float4 v = *(const float4*)&s2[(size_t)(base + n0 + r) * 64 + c4 * 4];
            if (c4 < 8) {
                int cb = c4 * 4;
                v.x = __expf(v.x - gm[cb + 0]);
                v.y = __expf(v.y - gm[cb + 1]);
                v.z = __expf(v.z - gm[cb + 2]);
                v.w = __expf(v.w - gm[cb + 3]);
                *(float4*)&ta[r][cb] = v;
            } else {
                *(float4*)&tx[r][(c4 - 8) * 4] = v;
            }
        }
        __syncthreads();
        #pragma unroll 5
        for (int n = 0; n < 25; n++) {
            float a   = ta[n][e];
            float4 xv = *(float4*)&tx[n][f4 * 4];
            a0 += a * xv.x; a1 += a * xv.y; a2 += a * xv.z; a3 += a * xv.w;
        }
    }
    *(float4*)&prods[((size_t)(g * 8 + ch)) * 1024 + e * 32 + f4 * 4] =
        make_float4(a0, a1, a2, a3);
}

// ---------------- Head: sum 8 chunk-partials, linear, softmax ----------------

__global__ __launch_bounds__(256) void k_head(const float* __restrict__ prods,
                                              const float* __restrict__ sinv,
                                              const float* __restrict__ Wlin,
                                              const float* __restrict__ blin,
                                              float* __restrict__ out) {
    __shared__ float red[4][NCLS];
    int g = (blockIdx.x & 7) + 8 * (blockIdx.x >> 3);
    if (g >= NB) return;
    int t = threadIdx.x;
    float p[NCLS];
    for (int c = 0; c < NCLS; c++) p[c] = 0.0f;
    const float* pg = &prods[(size_t)g * 8 * 1024];
    for (int j = 0; j < 4; j++) {
        int k = t * 4 + j;
        int e = k >> 5;
        float v = 0.0f;
        #pragma unroll
        for (int q = 0; q < 8; q++) v += pg[q * 1024 + k];
        v *= sinv[g * 32 + e];
        const float* wrow = &Wlin[k * NCLS];
        for (int c = 0; c < NCLS; c++) p[c] += v * wrow[c];
    }
    for (int off = 32; off > 0; off >>= 1)
        for (int c = 0; c < NCLS; c++) p[c] += __shfl_down(p[c], off, 64);
    int wave = t >> 6, lane = t & 63;
    if (lane == 0)
        for (int c = 0; c < NCLS; c++) red[wave][c] = p[c];
    __syncthreads();
    if (t == 0) {
        float logits[NCLS]; float mx = -1e30f;
        for (int c = 0; c < NCLS; c++) {
            logits[c] = red[0][c] + red[1][c] + red[2][c] + red[3][c] + blin[c];
            mx = fmaxf(mx, logits[c]);
        }
        float s = 0.0f;
        for (int c = 0; c < NCLS; c++) { logits[c] = expf(logits[c] - mx); s += logits[c]; }
        float inv = 1.0f / s;
        for (int c = 0; c < NCLS; c++) out[g * NCLS + c] = logits[c] * inv;
    }
}

// ---------------- launch ----------------

extern "C" void kernel_launch(void* const* d_in, const int* in_sizes, int n_in,
                              void* d_out, int out_size, void* d_ws, size_t ws_size,
                              hipStream_t stream) {
    const float* x    = (const float*)d_in[0];
    const int*   ei   = (const int*)d_in[1];
    const float* Wa1  = (const float*)d_in[3];
    const float* ba1  = (const float*)d_in[4];
    const float* Wa2  = (const float*)d_in[5];
    const float* ba2  = (const float*)d_in[6];
    const float* Wx1  = (const float*)d_in[7];
    const float* bx1  = (const float*)d_in[8];
    const float* Wx2  = (const float*)d_in[9];
    const float* bx2  = (const float*)d_in[10];
    const float* Wlin = (const float*)d_in[11];
    const float* blin = (const float*)d_in[12];
    float* out = (float*)d_out;

    char* w = (char*)d_ws;
    auto alloc = [&](size_t bytes) -> void* {
        void* p = (void*)w;
        w += (bytes + 255) & ~(size_t)255;
        return p;
    };
    int*            rowptr = (int*)alloc((N_NODES + 1) * sizeof(int));
    int*            cnt8   = (int*)alloc((size_t)8 * N_NODES * sizeof(int));
    float*          dinv   = (float*)alloc(N_NODES * sizeof(float));
    unsigned short* dh16   = (unsigned short*)alloc(N_NODES * sizeof(unsigned short));
    unsigned int*   esrc   = (unsigned int*)alloc((size_t)N_EDGES * sizeof(unsigned int));
    float*          gmax   = (float*)alloc(NB * DE * sizeof(float));
    float*          sinv   = (float*)alloc(NB * DE * sizeof(float));
    float*          prods  = (float*)alloc((size_t)NB * 8 * 1024 * sizeof(float));
    unsigned short* h16    = (unsigned short*)alloc((size_t)N_NODES * 128 * sizeof(unsigned short));
    unsigned short* b16    = (unsigned short*)alloc((size_t)N_NODES * 128 * sizeof(unsigned short));
    unsigned short* g16    = (unsigned short*)alloc((size_t)N_NODES * 64 * sizeof(unsigned short));
    float*          s2     = (float*)alloc((size_t)N_NODES * 64 * sizeof(float));

    const int* srcp = ei;
    const int* dstp = ei + N_EDGES;

    k_cnt<<<CNT_BLOCKS, 256, 0, stream>>>(dstp, cnt8);
    k_scan<<<8 * 13, 1024, 0, stream>>>(cnt8, rowptr, dinv, dh16);
    k_sg<<<SORT_BLOCKS + 8 * 13 * 4, 1024, 0, stream>>>(srcp, dstp, x, Wa1, Wx1,
                                                        rowptr, dh16, esrc, h16);
    k_agg128<<<8 * 13 * 250, 256, 0, stream>>>(h16, rowptr, esrc, dinv, ba1, bx1, b16);
    k_gemm2<<<8 * 13 * 16, 256, 0, stream>>>(b16, Wa2, Wx2, g16);
    k_agg64<<<8 * 13 * 250, 256, 0, stream>>>(g16, rowptr, esrc, dinv, ba2, bx2, s2);
    k_smax<<<8 * 13, 512, 0, stream>>>(s2, gmax, sinv);
    k_pool<<<8 * 13 * 8, 256, 0, stream>>>(s2, gmax, prods);
    k_head<<<8 * 13, 256, 0, stream>>>(prods, sinv, Wlin, blin, out);
}

// Round 5
// 303.047 us; speedup vs baseline: 1.2834x; 1.0773x over previous
//
#include <hip/hip_runtime.h>
#include <hip/hip_bf16.h>
#include <hip/hip_fp16.h>

#define N_NODES 100000
#define N_EDGES 3200000
#define NB      100
#define NPG     1000
#define EPG     32000    // edges per graph
#define DIN     128
#define DH      64
#define DE      32
#define NCLS    10
#define CNT_BLOCKS  832  // 8 slices x 104
#define SORT_BLOCKS 416  // 4 node-quarters x 104

// XCD-affine swizzle: graph g lives on XCD g%8 (blockIdx%8 = dispatch
// round-robin), keeping each graph's working set in ONE XCD's 4MB L2.
// Aggregation = PULL gather from L2 (R7). R14: packed (src|fp16 dinv) edge
// recs. R16: agg MACs via v_dot2_f32_f16 over edge pairs (DOT8).
// R17: gemm1 on MFMA (v_mfma_f32_16x16x32_f16).
// R18 FAILED: global-atomic scatter -> WRITE_SIZE 39->166MB (partial-line
// thrash). R19: parallel CSR build, LDS-staged scatter per node-quarter.
// R20: agg kernels restructured: was wave=1 node + 4-way edge-parallel +
// 16x shfl_xor reduce (=~250 wave-instr/node, 2-iter loop, VALU 66% but
// neither pipe saturated). Now a 16-lane GROUP owns one node (agg128;
// 8-lane group for agg64): each lane owns its 8 channels exclusively ->
// NO shuffle reduction, epilogue amortized across 4(8) nodes/wave, 8-edge
// unroll -> 8 gathers in flight. ~100 wave-instr/node.

typedef _Float16 h2_t __attribute__((ext_vector_type(2)));
typedef _Float16 h8_t __attribute__((ext_vector_type(8)));
typedef float    f4_t __attribute__((ext_vector_type(4)));

__device__ __forceinline__ float dot2f(unsigned a, unsigned b, float c) {
#if __has_builtin(__builtin_amdgcn_fdot2)
    return __builtin_amdgcn_fdot2(__builtin_bit_cast(h2_t, a),
                                  __builtin_bit_cast(h2_t, b), c, false);
#else
    float d;
    asm("v_dot2_f32_f16 %0, %1, %2, %3" : "=v"(d) : "v"(a), "v"(b), "v"(c));
    return d;
#endif
}

// rA = edge A uint4 (8 halfs), rB = edge B, dv = half2(dvA, dvB).
// perm sel: src1 bytes are idx 0..3, src0 bytes idx 4..7.
// 0x05040100 -> (lo16(rA), lo16(rB));  0x07060302 -> (hi16(rA), hi16(rB)).
#define DOT8(rA, rB, dv)                                                        \
    acc[0] = dot2f(__builtin_amdgcn_perm(rB.x, rA.x, 0x05040100u), dv, acc[0]); \
    acc[1] = dot2f(__builtin_amdgcn_perm(rB.x, rA.x, 0x07060302u), dv, acc[1]); \
    acc[2] = dot2f(__builtin_amdgcn_perm(rB.y, rA.y, 0x05040100u), dv, acc[2]); \
    acc[3] = dot2f(__builtin_amdgcn_perm(rB.y, rA.y, 0x07060302u), dv, acc[3]); \
    acc[4] = dot2f(__builtin_amdgcn_perm(rB.z, rA.z, 0x05040100u), dv, acc[4]); \
    acc[5] = dot2f(__builtin_amdgcn_perm(rB.z, rA.z, 0x07060302u), dv, acc[5]); \
    acc[6] = dot2f(__builtin_amdgcn_perm(rB.w, rA.w, 0x05040100u), dv, acc[6]); \
    acc[7] = dot2f(__builtin_amdgcn_perm(rB.w, rA.w, 0x07060302u), dv, acc[7]);

// ---------------- Phase 1: per-slice degree count ----------------

__global__ __launch_bounds__(256) void k_cnt(const int* __restrict__ dst,
                                             int* __restrict__ cnt8) {
    __shared__ int cnt[NPG];
    int slice = blockIdx.x >> 3;
    int g = (blockIdx.x & 7) + 8 * (slice % 13);
    int sub = slice / 13;                     // 0..7
    if (g >= NB) return;
    int t = threadIdx.x;
    for (int i = t; i < NPG; i += 256) cnt[i] = 0;
    __syncthreads();
    int ebase = g * EPG + sub * 4000, nbase = g * NPG;
    for (int i = t; i < 4000; i += 256)
        atomicAdd(&cnt[dst[ebase + i] - nbase], 1);
    __syncthreads();
    for (int i = t; i < NPG; i += 256)
        cnt8[sub * N_NODES + nbase + i] = cnt[i];
}

// ---------------- Phase 2: deg sum, scan -> rowptr, dinv/dh16 ----------------

__global__ __launch_bounds__(1024) void k_scan(const int* __restrict__ cnt8,
                                               int* __restrict__ rowptr,
                                               float* __restrict__ dinv,
                                               unsigned short* __restrict__ dh16) {
    __shared__ int sm[1024];
    int g = (blockIdx.x & 7) + 8 * (blockIdx.x >> 3);
    if (g >= NB) return;
    int t = threadIdx.x;
    int nbase = g * NPG, ebase = g * EPG;
    int v = 0;
    if (t < NPG) {
        #pragma unroll
        for (int s8 = 0; s8 < 8; s8++) v += cnt8[s8 * N_NODES + nbase + t];
        float dv = rsqrtf((float)v + 2.0f);
        dinv[nbase + t] = dv;
        dh16[nbase + t] = __half_as_ushort(__float2half_rn(dv));
    }
    sm[t] = v;
    __syncthreads();
    for (int off = 1; off < 1024; off <<= 1) {
        int xx = (t >= off) ? sm[t - off] : 0;
        __syncthreads();
        sm[t] += xx;
        __syncthreads();
    }
    if (t < NPG)
        rowptr[nbase + t] = ebase + sm[t] - v;
    if (g == NB - 1 && t == 0) rowptr[N_NODES] = N_EDGES;
}

// ---------------- Phase 3 fused: LDS-staged edge scatter + MFMA GEMM1 ----------------
// blocks [0,416): sort quarter (g,q) -- nodes [q*250,(q+1)*250).
// blocks [416, 832): gemm1, 250 rows each (16 waves x 16 rows).
// Edge record: uint32 = (src_local*16) | (fp16(dinv[src]) << 16).

union SharedSG {
    struct {
        int cur[256];                            // LDS cursors (local offsets)
        unsigned buf[10000];                     // staged records (cap >> max seg)
    } sc;
    struct {
        __align__(16) unsigned short wt[16384];  // fp16 W^T [c][k], swizzled
    } ge;
};

__global__ __launch_bounds__(1024) void k_sg(const int* __restrict__ src,
                                             const int* __restrict__ dst,
                                             const float* __restrict__ x,
                                             const float* __restrict__ Wa,
                                             const float* __restrict__ Wx,
                                             const int* __restrict__ rowptr,
                                             const unsigned short* __restrict__ dh16,
                                             unsigned int* __restrict__ esrc,
                                             unsigned short* __restrict__ h16) {
    __shared__ SharedSG S;
    int t = threadIdx.x;
    if (blockIdx.x < SORT_BLOCKS) {
        // ---------------- scatter path ----------------
        int xcd = blockIdx.x & 7, slot = blockIdx.x >> 3;
        int g = xcd + 8 * (slot % 13);
        int q = slot / 13;                       // node quarter 0..3
        if (g >= NB) return;
        int nbase = g * NPG, ebase = g * EPG;
        int n0 = q * 250;
        int base0 = rowptr[nbase + n0];
        int cap = rowptr[nbase + n0 + 250] - base0;
        if (t < 250)
            S.sc.cur[t] = rowptr[nbase + n0 + t] - base0;
        __syncthreads();
        for (int i = t; i < EPG; i += 1024) {
            int d = dst[ebase + i] - nbase - n0;
            if ((unsigned)d < 250u) {
                int s = src[ebase + i];
                int pos = atomicAdd(&S.sc.cur[d], 1);
                S.sc.buf[pos] = ((unsigned)(s - nbase) * 16) |
                                ((unsigned)dh16[s] << 16);
            }
        }
        __syncthreads();
        for (int i = t; i < cap; i += 1024)
            esrc[base0 + i] = S.sc.buf[i];
    } else {
        // ------------- gemm1 path (MFMA): h16 = fp16( x @ [W_a1 | W_x1] ) -------------
        int b2 = blockIdx.x - SORT_BLOCKS;         // 8*13*4 blocks
        int xcd = b2 & 7, slot = b2 >> 3;
        int g = xcd + 8 * (slot >> 2);
        int chunk = slot & 3;                       // 4 x 250-row chunks/graph
        if (g >= NB) return;
        int row0 = g * NPG + chunk * 250;
        // stage W^T fp16 in LDS, layout [c][k], byte ^= (c&7)<<4.
        {
            int cc = t & 127, kg = t >> 7;          // kg 0..7 -> k block of 16
            const float* Wp = (cc < 64) ? &Wa[cc] : &Wx[cc - 64];
            #pragma unroll
            for (int j = 0; j < 4; j++) {
                int k0 = kg * 16 + j * 4;
                union { __half h[4]; uint2 u; } pk;
                #pragma unroll
                for (int m = 0; m < 4; m++)
                    pk.h[m] = __float2half_rn(Wp[(k0 + m) * 64]);
                int byte = cc * 256 + ((2 * k0) ^ ((cc & 7) << 4));
                *(uint2*)((char*)S.ge.wt + byte) = pk.u;
            }
        }
        __syncthreads();
        int w = t >> 6, l = t & 63;
        int lr = l & 15, kq = l >> 4;               // A/B row|col, k-quarter
        int rowA = row0 + w * 16 + lr;
        int rA = rowA < N_NODES ? rowA : N_NODES - 1;
        const float* xr = &x[(size_t)rA * 128];
        h8_t a[4];
        #pragma unroll
        for (int kc = 0; kc < 4; kc++) {
            float4 lo = *(const float4*)&xr[kc * 32 + kq * 8];
            float4 hi = *(const float4*)&xr[kc * 32 + kq * 8 + 4];
            h8_t av;
            av[0] = (_Float16)lo.x; av[1] = (_Float16)lo.y;
            av[2] = (_Float16)lo.z; av[3] = (_Float16)lo.w;
            av[4] = (_Float16)hi.x; av[5] = (_Float16)hi.y;
            av[6] = (_Float16)hi.z; av[7] = (_Float16)hi.w;
            a[kc] = av;
        }
        f4_t acc[8] = {};
        #pragma unroll
        for (int kc = 0; kc < 4; kc++) {
            #pragma unroll
            for (int n = 0; n < 8; n++) {
                int cc = n * 16 + lr;
                int byte = cc * 256 + (((kc * 32 + kq * 8) * 2) ^ ((cc & 7) << 4));
                h8_t bf = *(h8_t*)((char*)S.ge.wt + byte);
                acc[n] = __builtin_amdgcn_mfma_f32_16x16x32_f16(a[kc], bf, acc[n], 0, 0, 0);
            }
        }
        // D: col = lane&15 (=lr), row = 4*kq + reg
        int rowD = row0 + w * 16 + kq * 4;
        #pragma unroll
        for (int n = 0; n < 8; n++) {
            #pragma unroll
            for (int j = 0; j < 4; j++) {
                int r = rowD + j;
                if (r < N_NODES)
                    h16[(size_t)r * 128 + n * 16 + lr] =
                        __half_as_ushort(__float2half_rn(acc[n][j]));
            }
        }
    }
}

// ---------------- Aggregation, 128 channels (layer 1) ----------------
// R20: 16-lane group = 1 node; lane owns 8 channels (cl = uint4 group).
// 16 nodes/block, no cross-lane reduction. 8-edge unrolled gather loop.

__global__ __launch_bounds__(256) void k_agg128(const unsigned short* __restrict__ h16,
                                                const int* __restrict__ rowptr,
                                                const unsigned int* __restrict__ esrc,
                                                const float* __restrict__ dinv,
                                                const float* __restrict__ ba,
                                                const float* __restrict__ bx,
                                                unsigned short* __restrict__ outB16) {
    int xcd = blockIdx.x & 7, slot = blockIdx.x >> 3;
    int gi = slot / 63, chunk = slot - gi * 63;   // 63 chunks x 16 nodes
    int g = xcd + 8 * gi;
    if (g >= NB) return;
    int grp = threadIdx.x >> 4;    // node within block 0..15
    int cl  = threadIdx.x & 15;    // uint4 channel group
    int nl  = chunk * 16 + grp;
    int valid = nl < NPG;
    int nlc = valid ? nl : NPG - 1;
    int wid = g * NPG + nlc;
    const uint4* hg4 = (const uint4*)(h16 + g * NPG * 128);
    float acc[8] = {};
    union U8 { uint4 u; __half h[8]; };
    int e0 = rowptr[wid];
    int e1 = valid ? rowptr[wid + 1] : e0;
    int e = e0;
    for (; e + 8 <= e1; e += 8) {
        unsigned pv0 = esrc[e + 0], pv1 = esrc[e + 1];
        unsigned pv2 = esrc[e + 2], pv3 = esrc[e + 3];
        unsigned pv4 = esrc[e + 4], pv5 = esrc[e + 5];
        unsigned pv6 = esrc[e + 6], pv7 = esrc[e + 7];
        uint4 r0 = hg4[(pv0 & 0xffffu) + cl];
        uint4 r1 = hg4[(pv1 & 0xffffu) + cl];
        uint4 r2 = hg4[(pv2 & 0xffffu) + cl];
        uint4 r3 = hg4[(pv3 & 0xffffu) + cl];
        uint4 r4 = hg4[(pv4 & 0xffffu) + cl];
        uint4 r5 = hg4[(pv5 & 0xffffu) + cl];
        uint4 r6 = hg4[(pv6 & 0xffffu) + cl];
        uint4 r7 = hg4[(pv7 & 0xffffu) + cl];
        unsigned dA = __builtin_amdgcn_perm(pv1, pv0, 0x07060302u);
        unsigned dB = __builtin_amdgcn_perm(pv3, pv2, 0x07060302u);
        unsigned dC = __builtin_amdgcn_perm(pv5, pv4, 0x07060302u);
        unsigned dD = __builtin_amdgcn_perm(pv7, pv6, 0x07060302u);
        DOT8(r0, r1, dA);
        DOT8(r2, r3, dB);
        DOT8(r4, r5, dC);
        DOT8(r6, r7, dD);
    }
    for (; e + 2 <= e1; e += 2) {
        unsigned pv0 = esrc[e], pv1 = esrc[e + 1];
        uint4 r0 = hg4[(pv0 & 0xffffu) + cl];
        uint4 r1 = hg4[(pv1 & 0xffffu) + cl];
        unsigned dA = __builtin_amdgcn_perm(pv1, pv0, 0x07060302u);
        DOT8(r0, r1, dA);
    }
    if (e < e1) {
        unsigned pv = esrc[e];
        uint4 r = hg4[(pv & 0xffffu) + cl];
        unsigned dA = pv >> 16;            // (dv, 0)
        DOT8(r, r, dA);
    }
    // epilogue (all lanes; no shuffles)
    float di = dinv[wid];
    float sw = 2.0f * di * di;
    U8 hv; hv.u = hg4[nlc * 16 + cl];
    int cl8 = cl * 8;
    const float* bb = (cl8 < 64) ? &ba[cl8] : &bx[cl8 - 64];
    union { __half2 h[4]; uint4 q; } pk;
    #pragma unroll
    for (int k = 0; k < 4; k++) {
        float ox = fmaxf(di * acc[2 * k]     + sw * __half2float(hv.h[2 * k])     + bb[2 * k],     0.0f);
        float oy = fmaxf(di * acc[2 * k + 1] + sw * __half2float(hv.h[2 * k + 1]) + bb[2 * k + 1], 0.0f);
        pk.h[k] = __floats2half2_rn(ox, oy);
    }
    if (valid)
        *(uint4*)&outB16[(size_t)wid * 128 + cl8] = pk.q;
}

// ---------------- Aggregation, 64 channels (layer 2) ----------------
// R20: 8-lane group = 1 node; lane owns 8 channels. 32 nodes/block.

__global__ __launch_bounds__(256) void k_agg64(const unsigned short* __restrict__ g16,
                                               const int* __restrict__ rowptr,
                                               const unsigned int* __restrict__ esrc,
                                               const float* __restrict__ dinv,
                                               const float* __restrict__ ba2,
                                               const float* __restrict__ bx2,
                                               float* __restrict__ s2) {
    int xcd = blockIdx.x & 7, slot = blockIdx.x >> 3;
    int gi = slot >> 5, chunk = slot & 31;        // 32 chunks x 32 nodes
    int g = xcd + 8 * gi;
    if (g >= NB) return;
    int grp = threadIdx.x >> 3;    // node within block 0..31
    int cl  = threadIdx.x & 7;     // uint4 channel group
    int nl  = chunk * 32 + grp;
    int valid = nl < NPG;
    int nlc = valid ? nl : NPG - 1;
    int wid = g * NPG + nlc;
    const uint4* gg4 = (const uint4*)(g16 + g * NPG * 64);
    float acc[8] = {};
    union U8 { uint4 u; __half h[8]; };
    int e0 = rowptr[wid];
    int e1 = valid ? rowptr[wid + 1] : e0;
    int e = e0;
    for (; e + 8 <= e1; e += 8) {
        unsigned pv0 = esrc[e + 0], pv1 = esrc[e + 1];
        unsigned pv2 = esrc[e + 2], pv3 = esrc[e + 3];
        unsigned pv4 = esrc[e + 4], pv5 = esrc[e + 5];
        unsigned pv6 = esrc[e + 6], pv7 = esrc[e + 7];
        uint4 r0 = gg4[((pv0 & 0xffffu) >> 1) + cl];
        uint4 r1 = gg4[((pv1 & 0xffffu) >> 1) + cl];
        uint4 r2 = gg4[((pv2 & 0xffffu) >> 1) + cl];
        uint4 r3 = gg4[((pv3 & 0xffffu) >> 1) + cl];
        uint4 r4 = gg4[((pv4 & 0xffffu) >> 1) + cl];
        uint4 r5 = gg4[((pv5 & 0xffffu) >> 1) + cl];
        uint4 r6 = gg4[((pv6 & 0xffffu) >> 1) + cl];
        uint4 r7 = gg4[((pv7 & 0xffffu) >> 1) + cl];
        unsigned dA = __builtin_amdgcn_perm(pv1, pv0, 0x07060302u);
        unsigned dB = __builtin_amdgcn_perm(pv3, pv2, 0x07060302u);
        unsigned dC = __builtin_amdgcn_perm(pv5, pv4, 0x07060302u);
        unsigned dD = __builtin_amdgcn_perm(pv7, pv6, 0x07060302u);
        DOT8(r0, r1, dA);
        DOT8(r2, r3, dB);
        DOT8(r4, r5, dC);
        DOT8(r6, r7, dD);
    }
    for (; e + 2 <= e1; e += 2) {
        unsigned pv0 = esrc[e], pv1 = esrc[e + 1];
        uint4 r0 = gg4[((pv0 & 0xffffu) >> 1) + cl];
        uint4 r1 = gg4[((pv1 & 0xffffu) >> 1) + cl];
        unsigned dA = __builtin_amdgcn_perm(pv1, pv0, 0x07060302u);
        DOT8(r0, r1, dA);
    }
    if (e < e1) {
        unsigned pv = esrc[e];
        uint4 r = gg4[((pv & 0xffffu) >> 1) + cl];
        unsigned dA = pv >> 16;
        DOT8(r, r, dA);
    }
    float di = dinv[wid];
    float sw = 2.0f * di * di;
    U8 hv; hv.u = gg4[nlc * 8 + cl];
    int cl8 = cl * 8;
    float o[8];
    #pragma unroll
    for (int k = 0; k < 8; k++)
        o[k] = di * acc[k] + sw * __half2float(hv.h[k]);
    if (cl8 < 32) {
        #pragma unroll
        for (int k = 0; k < 8; k++) o[k] += ba2[cl8 + k];
    } else {
        #pragma unroll
        for (int k = 0; k < 8; k++) o[k] = fmaxf(o[k] + bx2[cl8 - 32 + k], 0.0f);
    }
    if (valid) {
        *(float4*)&s2[(size_t)wid * 64 + cl8]     = make_float4(o[0], o[1], o[2], o[3]);
        *(float4*)&s2[(size_t)wid * 64 + cl8 + 4] = make_float4(o[4], o[5], o[6], o[7]);
    }
}

// ---------------- GEMM 2: g16 = fp16( [a1|x1] @ blockdiag(W_a2, W_x2) ) ----------------

__global__ __launch_bounds__(256) void k_gemm2(const unsigned short* __restrict__ Bm16,
                                               const float* __restrict__ Wa2,
                                               const float* __restrict__ Wx2,
                                               unsigned short* __restrict__ g16) {
    __shared__ float xs[64][132];
    __shared__ float ws[64][68];
    int xcd = blockIdx.x & 7, slot = blockIdx.x >> 3;
    int g = xcd + 8 * (slot >> 4);
    int chunk = slot & 15;
    if (g >= NB) return;
    int row0 = g * NPG + chunk * 64;   // chunk 15 spills into next graph: benign dup
    int t = threadIdx.x;
    for (int i = 0; i < 4; i++) {
        int idx = t + 256 * i;
        int k = idx >> 4, c4 = idx & 15, c = c4 * 4;
        float4 v;
        if (c < 32) v = *(const float4*)&Wa2[k * 32 + c];
        else        v = *(const float4*)&Wx2[k * 32 + (c - 32)];
        *(float4*)&ws[k][c] = v;
    }
    for (int i = 0; i < 4; i++) {
        int idx = t + 256 * i;          // 1024 uint4s = 64 rows x 16 groups
        int r = idx >> 4, c8 = idx & 15;
        int rr = row0 + r; if (rr >= N_NODES) rr = N_NODES - 1;
        union { uint4 u; __half2 h[4]; } pk;
        pk.u = *(const uint4*)&Bm16[(size_t)rr * 128 + c8 * 8];
        float2 f0 = __half22float2(pk.h[0]);
        float2 f1 = __half22float2(pk.h[1]);
        float2 f2 = __half22float2(pk.h[2]);
        float2 f3 = __half22float2(pk.h[3]);
        int cb = c8 * 8;
        *(float4*)&xs[r][cb]     = make_float4(f0.x, f0.y, f1.x, f1.y);
        *(float4*)&xs[r][cb + 4] = make_float4(f2.x, f2.y, f3.x, f3.y);
    }
    __syncthreads();
    int cg = t & 15, rg = t >> 4;
    int koff = (cg < 8) ? 0 : 64;
    float acc[4][4] = {};
    for (int k = 0; k < 64; k++) {
        float4 w = *(float4*)&ws[k][cg * 4];
        float xv[4];
        for (int i = 0; i < 4; i++) xv[i] = xs[rg * 4 + i][koff + k];
        for (int i = 0; i < 4; i++) {
            acc[i][0] += xv[i] * w.x; acc[i][1] += xv[i] * w.y;
            acc[i][2] += xv[i] * w.z; acc[i][3] += xv[i] * w.w;
        }
    }
    for (int i = 0; i < 4; i++) {
        int r = row0 + rg * 4 + i;
        if (r < N_NODES) {
            union { ushort4 u; __half2 h[2]; } pk;
            pk.h[0] = __floats2half2_rn(acc[i][0], acc[i][1]);
            pk.h[1] = __floats2half2_rn(acc[i][2], acc[i][3]);
            *(ushort4*)&g16[(size_t)r * 64 + cg * 4] = pk.u;
        }
    }
}

// ---------------- Segment softmax stats (cols 0..31), 512 threads ----------------

__global__ __launch_bounds__(512) void k_smax(const float* __restrict__ s2,
                                              float* __restrict__ gmax,
                                              float* __restrict__ sinv) {
    __shared__ float red[16][32];
    int g = (blockIdx.x & 7) + 8 * (blockIdx.x >> 3);
    if (g >= NB) return;
    int t = threadIdx.x;
    int c = t & 31, sub = t >> 5;     // 16 row-subsets
    size_t base = (size_t)g * NPG;
    float m = -1e30f;
    for (int n = sub; n < NPG; n += 16)
        m = fmaxf(m, s2[(base + n) * 64 + c]);
    red[sub][c] = m; __syncthreads();
    if (sub == 0) {
        for (int j = 1; j < 16; j++) m = fmaxf(m, red[j][c]);
        red[0][c] = m;
        gmax[g * 32 + c] = m;
    }
    __syncthreads();
    m = red[0][c];
    __syncthreads();
    float sum = 0.0f;
    for (int n = sub; n < NPG; n += 16)
        sum += __expf(s2[(base + n) * 64 + c] - m);
    red[sub][c] = sum; __syncthreads();
    if (sub == 0) {
        for (int j = 1; j < 16; j++) sum += red[j][c];
        sinv[g * 32 + c] = 1.0f / sum;
    }
}

// ---------------- Bilinear pool: 8 chunks/graph, 25-row tiles ----------------

__global__ __launch_bounds__(256) void k_pool(const float* __restrict__ s2,
                                              const float* __restrict__ gmax,
                                              float* __restrict__ prods) {
    __shared__ float ta[25][32];
    __shared__ float tx[25][32];
    __shared__ float gm[32];
    int xcd = blockIdx.x & 7, slot = blockIdx.x >> 3;
    int g = xcd + 8 * (slot >> 3);
    int ch = slot & 7;
    if (g >= NB) return;
    int t = threadIdx.x;
    if (t < 32) gm[t] = gmax[g * 32 + t];
    int e  = t >> 3;
    int f4 = t & 7;
    float a0 = 0.f, a1 = 0.f, a2 = 0.f, a3 = 0.f;
    int base = g * NPG + ch * 125;
    for (int n0 = 0; n0 < 125; n0 += 25) {
        __syncthreads();
        for (int i = t; i < 25 * 16; i += 256) {
            int r = i >> 4, c4 = i & 15;
            float4 v = *(const float4*)&s2[(size_t)(base + n0 + r) * 64 + c4 * 4];
            if (c4 < 8) {
                int cb = c4 * 4;
                v.x = __expf(v.x - gm[cb + 0]);
                v.y = __expf(v.y - gm[cb + 1]);
                v.z = __expf(v.z - gm[cb + 2]);
                v.w = __expf(v.w - gm[cb + 3]);
                *(float4*)&ta[r][cb] = v;
            } else {
                *(float4*)&tx[r][(c4 - 8) * 4] = v;
            }
        }
        __syncthreads();
        #pragma unroll 5
        for (int n = 0; n < 25; n++) {
            float a   = ta[n][e];
            float4 xv = *(float4*)&tx[n][f4 * 4];
            a0 += a * xv.x; a1 += a * xv.y; a2 += a * xv.z; a3 += a * xv.w;
        }
    }
    *(float4*)&prods[((size_t)(g * 8 + ch)) * 1024 + e * 32 + f4 * 4] =
        make_float4(a0, a1, a2, a3);
}

// ---------------- Head: sum 8 chunk-partials, linear, softmax ----------------

__global__ __launch_bounds__(256) void k_head(const float* __restrict__ prods,
                                              const float* __restrict__ sinv,
                                              const float* __restrict__ Wlin,
                                              const float* __restrict__ blin,
                                              float* __restrict__ out) {
    __shared__ float red[4][NCLS];
    int g = (blockIdx.x & 7) + 8 * (blockIdx.x >> 3);
    if (g >= NB) return;
    int t = threadIdx.x;
    float p[NCLS];
    for (int c = 0; c < NCLS; c++) p[c] = 0.0f;
    const float* pg = &prods[(size_t)g * 8 * 1024];
    for (int j = 0; j < 4; j++) {
        int k = t * 4 + j;
        int e = k >> 5;
        float v = 0.0f;
        #pragma unroll
        for (int q = 0; q < 8; q++) v += pg[q * 1024 + k];
        v *= sinv[g * 32 + e];
        const float* wrow = &Wlin[k * NCLS];
        for (int c = 0; c < NCLS; c++) p[c] += v * wrow[c];
    }
    for (int off = 32; off > 0; off >>= 1)
        for (int c = 0; c < NCLS; c++) p[c] += __shfl_down(p[c], off, 64);
    int wave = t >> 6, lane = t & 63;
    if (lane == 0)
        for (int c = 0; c < NCLS; c++) red[wave][c] = p[c];
    __syncthreads();
    if (t == 0) {
        float logits[NCLS]; float mx = -1e30f;
        for (int c = 0; c < NCLS; c++) {
            logits[c] = red[0][c] + red[1][c] + red[2][c] + red[3][c] + blin[c];
            mx = fmaxf(mx, logits[c]);
        }
        float s = 0.0f;
        for (int c = 0; c < NCLS; c++) { logits[c] = expf(logits[c] - mx); s += logits[c]; }
        float inv = 1.0f / s;
        for (int c = 0; c < NCLS; c++) out[g * NCLS + c] = logits[c] * inv;
    }
}

// ---------------- launch ----------------

extern "C" void kernel_launch(void* const* d_in, const int* in_sizes, int n_in,
                              void* d_out, int out_size, void* d_ws, size_t ws_size,
                              hipStream_t stream) {
    const float* x    = (const float*)d_in[0];
    const int*   ei   = (const int*)d_in[1];
    const float* Wa1  = (const float*)d_in[3];
    const float* ba1  = (const float*)d_in[4];
    const float* Wa2  = (const float*)d_in[5];
    const float* ba2  = (const float*)d_in[6];
    const float* Wx1  = (const float*)d_in[7];
    const float* bx1  = (const float*)d_in[8];
    const float* Wx2  = (const float*)d_in[9];
    const float* bx2  = (const float*)d_in[10];
    const float* Wlin = (const float*)d_in[11];
    const float* blin = (const float*)d_in[12];
    float* out = (float*)d_out;

    char* w = (char*)d_ws;
    auto alloc = [&](size_t bytes) -> void* {
        void* p = (void*)w;
        w += (bytes + 255) & ~(size_t)255;
        return p;
    };
    int*            rowptr = (int*)alloc((N_NODES + 1) * sizeof(int));
    int*            cnt8   = (int*)alloc((size_t)8 * N_NODES * sizeof(int));
    float*          dinv   = (float*)alloc(N_NODES * sizeof(float));
    unsigned short* dh16   = (unsigned short*)alloc(N_NODES * sizeof(unsigned short));
    unsigned int*   esrc   = (unsigned int*)alloc((size_t)N_EDGES * sizeof(unsigned int));
    float*          gmax   = (float*)alloc(NB * DE * sizeof(float));
    float*          sinv   = (float*)alloc(NB * DE * sizeof(float));
    float*          prods  = (float*)alloc((size_t)NB * 8 * 1024 * sizeof(float));
    unsigned short* h16    = (unsigned short*)alloc((size_t)N_NODES * 128 * sizeof(unsigned short));
    unsigned short* b16    = (unsigned short*)alloc((size_t)N_NODES * 128 * sizeof(unsigned short));
    unsigned short* g16    = (unsigned short*)alloc((size_t)N_NODES * 64 * sizeof(unsigned short));
    float*          s2     = (float*)alloc((size_t)N_NODES * 64 * sizeof(float));

    const int* srcp = ei;
    const int* dstp = ei + N_EDGES;

    k_cnt<<<CNT_BLOCKS, 256, 0, stream>>>(dstp, cnt8);
    k_scan<<<8 * 13, 1024, 0, stream>>>(cnt8, rowptr, dinv, dh16);
    k_sg<<<SORT_BLOCKS + 8 * 13 * 4, 1024, 0, stream>>>(srcp, dstp, x, Wa1, Wx1,
                                                        rowptr, dh16, esrc, h16);
    k_agg128<<<8 * 13 * 63, 256, 0, stream>>>(h16, rowptr, esrc, dinv, ba1, bx1, b16);
    k_gemm2<<<8 * 13 * 16, 256, 0, stream>>>(b16, Wa2, Wx2, g16);
    k_agg64<<<8 * 13 * 32, 256, 0, stream>>>(g16, rowptr, esrc, dinv, ba2, bx2, s2);
    k_smax<<<8 * 13, 512, 0, stream>>>(s2, gmax, sinv);
    k_pool<<<8 * 13 * 8, 256, 0, stream>>>(s2, gmax, prods);
    k_head<<<8 * 13, 256, 0, stream>>>(prods, sinv, Wlin, blin, out);
}